// Round 2
// 329.316 us; speedup vs baseline: 1.0453x; 1.0453x over previous
//
#include <hip/hip_runtime.h>

typedef unsigned short ushort_t;
typedef short v8s __attribute__((ext_vector_type(8)));   // 8 bf16 (4 VGPRs)
typedef float v4f __attribute__((ext_vector_type(4)));   // MFMA acc

#define BATCH    65536
#define UNITS    256
#define M_TILE   32
#define KSTEPS   16
#define BCHUNK   10240      // shorts per packed-K chunk: 256 cols * (32k + 8 pad)
#define T_STRIDE 264        // shorts per LDS tile row (528 B, 16B-aligned, 2-way banks)
#define LDS_HB   0
#define LDS_GT   16896
#define LDS_SC   33792
#define LDS_TOT  35200

__device__ __forceinline__ float b2f(ushort_t u) {
    union { unsigned int i; float f; } v; v.i = ((unsigned int)u) << 16; return v.f;
}
__device__ __forceinline__ ushort_t f2b(float f) {
    union { float f; unsigned int i; } v; v.f = f;
    unsigned int r = (v.i + 0x7fffu + ((v.i >> 16) & 1u)) >> 16;   // RNE
    return (ushort_t)r;
}

// ---- weight pre-pack: fp32 W[512][256] -> bf16 per-chunk [n][kl] -----------
// chunk c = k>>5 holds cols n=0..255, each 32 k-values + 8 pad (16B-aligned)
__global__ void pack_w(const float* __restrict__ w_in,
                       const float* __restrict__ w_rec,
                       ushort_t* __restrict__ Wp) {
    int gid = blockIdx.x * 256 + threadIdx.x;      // 0..131071
    int k = gid >> 8, n = gid & 255;
    float v = (k < 256) ? w_in[k * 256 + n] : w_rec[(k - 256) * 256 + n];
    Wp[(size_t)(k >> 5) * BCHUNK + n * 40 + (k & 31)] = f2b(v);
}

// ---- fused cell ------------------------------------------------------------
// M_TILE=32: LDS 35.2 KB -> 4 blocks/CU -> 16 waves/CU (was 2 blocks / 8 waves)
__global__ __launch_bounds__(256, 4)
void fused_cell(const float* __restrict__ inputs,
                const float* __restrict__ prev_h,
                const float* __restrict__ prev_G,
                const float* __restrict__ prev_phase,
                const ushort_t* __restrict__ Wp,
                const float* __restrict__ bias,
                float* __restrict__ out) {
    __shared__ __align__(16) char smem[LDS_TOT];
    short* Hb     = (short*)(smem + LDS_HB);      // 32 x 264 bf16 prev_h (orig order)
    short* Gt     = (short*)(smem + LDS_GT);      // 32 x 264 bf16 new_G
    float* r_mean = (float*)(smem + LDS_SC);
    float* r_rstd = r_mean + 32;
    float* r_comb = r_rstd + 32;
    float* bias_f = r_comb + 32;

    const int tid  = threadIdx.x;
    const int row0 = blockIdx.x * M_TILE;

    float* outH = out;
    float* outG = out + (size_t)BATCH * UNITS;
    float* outP = out + (size_t)2 * BATCH * UNITS;

    bias_f[tid] = bias[tid];

    // ---- phase 1: new_G = 0.9*prev_G + 0.1*roll(prev_h), stats, oscillator
    // 8 lanes per row (tid>>3 = row, tid&7 = 32-col slice): coalesced 128B
    // segments, 9 shuffles/thread (was 288), stats on 32 parallel threads.
    {
        const int lr = tid >> 3;
        const int p  = tid & 7;
        const int gr = row0 + lr;
        float s1 = 0.f, s2 = 0.f, sh = 0.f;
        #pragma unroll
        for (int i = 0; i < 8; ++i) {
            int c0 = i * 32 + p * 4;
            int pc = (c0 + 128) & 255;        // raw[:,c] = prev_h[:,(c+128)&255]
            float4 hp = *(const float4*)(prev_h + (size_t)gr * UNITS + pc);
            float4 gp = *(const float4*)(prev_G + (size_t)gr * UNITS + c0);
            float4 ng;
            ng.x = 0.9f * gp.x + 0.1f * hp.x;
            ng.y = 0.9f * gp.y + 0.1f * hp.y;
            ng.z = 0.9f * gp.z + 0.1f * hp.z;
            ng.w = 0.9f * gp.w + 0.1f * hp.w;
            s1 += ng.x + ng.y + ng.z + ng.w;
            s2 += ng.x*ng.x + ng.y*ng.y + ng.z*ng.z + ng.w*ng.w;
            sh += hp.x + hp.y + hp.z + hp.w;
            *(float4*)(outG + (size_t)gr * UNITS + c0) = ng;      // output 1 (fp32)
            ushort4 gq; gq.x = f2b(ng.x); gq.y = f2b(ng.y); gq.z = f2b(ng.z); gq.w = f2b(ng.w);
            *(ushort4*)(Gt + lr * T_STRIDE + c0) = gq;            // epilogue copy
            ushort4 hq; hq.x = f2b(hp.x); hq.y = f2b(hp.y); hq.z = f2b(hp.z); hq.w = f2b(hp.w);
            *(ushort4*)(Hb + lr * T_STRIDE + pc) = hq;            // orig-order bf16 prev_h
        }
        #pragma unroll
        for (int off = 4; off > 0; off >>= 1) {
            s1 += __shfl_xor(s1, off, 64);
            s2 += __shfl_xor(s2, off, 64);
            sh += __shfl_xor(sh, off, 64);
        }
        if (p == 0) {
            float mean = s1 * (1.f / 256.f);
            float var  = s2 * (1.f / 256.f) - mean * mean;         // population var
            float rstd = 1.f / (sqrtf(fmaxf(var, 0.f)) + 1e-6f);
            float np   = prev_phase[gr] + 0.2513274122871834591f;  // 2*pi/25
            outP[gr] = np;                                          // output 2 (fp32)
            float comb = sinf(np) + 0.05f * (sh * (1.f / 256.f) - 0.1f);
            r_mean[lr] = mean; r_rstd[lr] = rstd; r_comb[lr] = comb;
        }
    }

    __syncthreads();   // Hb + Gt + scalars visible

    // ---- phase 2: GEMM z = [inputs|prev_h] @ [w_in;w_rec]  (bf16 MFMA)
    // 16x16x32: A[m=lane&15][k=q*8+j]; B[k=q*8+j][n=lane&15]; C: col=lane&15,row=q*4+reg
    // wave w: row-group rg = w&1 (16 rows), col-half ch = w>>1 (128 cols, 8 tiles)
    const int l   = tid & 63;
    const int w   = tid >> 6;
    const int n16 = l & 15;
    const int q   = l >> 4;
    const int rg  = w & 1;
    const int ch  = w >> 1;

    v4f acc[8];
    const v4f z4 = {0.f, 0.f, 0.f, 0.f};
    #pragma unroll
    for (int t = 0; t < 8; ++t) acc[t] = z4;

    const int arow = rg * 16 + n16;
    const float* ainp = inputs + (size_t)(row0 + arow) * UNITS + q * 8;
    const short* hbp  = Hb + arow * T_STRIDE + q * 8;
    const short* bp   = (const short*)Wp + (ch * 128 + n16) * 40 + q * 8;

    #pragma unroll 2
    for (int s = 0; s < KSTEPS; ++s) {
        v8s a;
        if (s < 8) {
            float4 f0 = *(const float4*)(ainp + s * 32);
            float4 f1 = *(const float4*)(ainp + s * 32 + 4);
            a[0] = (short)f2b(f0.x); a[1] = (short)f2b(f0.y);
            a[2] = (short)f2b(f0.z); a[3] = (short)f2b(f0.w);
            a[4] = (short)f2b(f1.x); a[5] = (short)f2b(f1.y);
            a[6] = (short)f2b(f1.z); a[7] = (short)f2b(f1.w);
        } else {
            a = *(const v8s*)(hbp + (s - 8) * 32);
        }
        const short* bs = bp + s * BCHUNK;
        #pragma unroll
        for (int t = 0; t < 8; ++t) {
            v8s b = *(const v8s*)(bs + t * 640);   // col = ch*128 + t*16 + n16
            acc[t] = __builtin_amdgcn_mfma_f32_16x16x32_bf16(a, b, acc[t], 0, 0, 0);
        }
    }

    // ---- epilogue: field_effect * (dot+bias) -> elu -> inertia -> clip
    #pragma unroll
    for (int t = 0; t < 8; ++t) {
        int c = ch * 128 + t * 16 + n16;
        float bz = bias_f[c];
        #pragma unroll
        for (int r = 0; r < 4; ++r) {
            int lr = rg * 16 + q * 4 + r;
            int gr = row0 + lr;
            float gval = b2f((ushort_t)Gt[lr * T_STRIDE + c]);
            float gn = (gval - r_mean[lr]) * r_rstd[lr];
            float e2 = __expf(2.f * gn);                       // tanh via exp
            float th = 1.f - 2.f / (e2 + 1.f);
            float field = 1.f + 0.5f * r_comb[lr] * th;
            float z = (acc[t][r] + bz) * field;
            float el = (z > 0.f) ? z : (__expf(z) - 1.f);
            float h = 0.9f * b2f((ushort_t)Hb[lr * T_STRIDE + c]) + 0.1f * el;
            h = fminf(fmaxf(h, -20.f), 20.f);
            outH[(size_t)gr * UNITS + c] = h;                  // output 0 (fp32)
        }
    }
}

extern "C" void kernel_launch(void* const* d_in, const int* in_sizes, int n_in,
                              void* d_out, int out_size, void* d_ws, size_t ws_size,
                              hipStream_t stream) {
    const float* inputs     = (const float*)d_in[0];
    const float* prev_h     = (const float*)d_in[1];
    const float* prev_G     = (const float*)d_in[2];
    const float* prev_phase = (const float*)d_in[3];
    const float* w_in       = (const float*)d_in[4];
    const float* w_rec      = (const float*)d_in[5];
    const float* bias       = (const float*)d_in[6];
    float* out    = (float*)d_out;
    ushort_t* Wp  = (ushort_t*)d_ws;       // 327,680 B packed bf16 weights

    pack_w<<<512, 256, 0, stream>>>(w_in, w_rec, Wp);
    fused_cell<<<BATCH / M_TILE, 256, 0, stream>>>(inputs, prev_h, prev_G,
                                                   prev_phase, Wp, bias, out);
}

// Round 3
// 318.056 us; speedup vs baseline: 1.0823x; 1.0354x over previous
//
#include <hip/hip_runtime.h>

typedef unsigned short ushort_t;
typedef short v8s __attribute__((ext_vector_type(8)));   // 8 bf16 (4 VGPRs)
typedef float v4f __attribute__((ext_vector_type(4)));   // MFMA acc

#define BATCH    65536
#define UNITS    256
#define M_TILE   32
#define A_PAD    33          // rows+1 pad per 16B-fragment column: breaks pow2 banks
#define GT_STRIDE 264
#define LDS_A    0
#define LDS_A_SZ (64 * A_PAD * 16)        // 33,792 B : [k>>3][row pad33][8 shorts]
#define LDS_GT   LDS_A_SZ                 // 32 x 264 bf16 new_G
#define LDS_GT_SZ (32 * GT_STRIDE * 2)    // 16,896 B
#define LDS_SC   (LDS_GT + LDS_GT_SZ)     // 50,688
#define LDS_TOT  (LDS_SC + 1408)          // 52,096 B -> 3 blocks/CU

__device__ __forceinline__ float b2f(ushort_t u) {
    union { unsigned int i; float f; } v; v.i = ((unsigned int)u) << 16; return v.f;
}
__device__ __forceinline__ ushort_t f2b(float f) {
    union { float f; unsigned int i; } v; v.f = f;
    unsigned int r = (v.i + 0x7fffu + ((v.i >> 16) & 1u)) >> 16;   // RNE
    return (ushort_t)r;
}

// ---- weight pre-pack: fp32 W[512][256] -> bf16 MFMA-fragment order ---------
// B frag for (kchunk s = k>>5, tile t = n>>4): lane l = q*16+n16 holds
// B[k = s*32+q*8+j][n = t*16+n16], j=0..7.  Layout [s][t][l][8] -> a wave's
// B load is base + l*16B: perfectly coalesced 1KB, sequential lines.
__global__ void pack_w(const float* __restrict__ w_in,
                       const float* __restrict__ w_rec,
                       ushort_t* __restrict__ Wp) {
    int gid = blockIdx.x * 256 + threadIdx.x;      // 0..131071
    int k = gid >> 8, n = gid & 255;
    float v = (k < 256) ? w_in[k * 256 + n] : w_rec[(k - 256) * 256 + n];
    int s = k >> 5, t = n >> 4;
    int lane = ((k >> 3) & 3) * 16 + (n & 15);
    Wp[(size_t)(((s * 16 + t) * 64) + lane) * 8 + (k & 7)] = f2b(v);
}

// ---- fused cell ------------------------------------------------------------
// Each wave: all 32 rows x 64 cols (acc[2][4]) -> each B fragment read by
// exactly ONE wave (B traffic per block halves vs row-split).  A operands
// (inputs bf16 + prev_h bf16) staged K-major in LDS by phase 1: zero f2b in
// the K-loop, conflict-free contiguous ds_read_b128.
__global__ __launch_bounds__(256, 3)
void fused_cell(const float* __restrict__ inputs,
                const float* __restrict__ prev_h,
                const float* __restrict__ prev_G,
                const float* __restrict__ prev_phase,
                const ushort_t* __restrict__ Wp,
                const float* __restrict__ bias,
                float* __restrict__ out) {
    __shared__ __align__(16) char smem[LDS_TOT];
    short* Ak     = (short*)(smem + LDS_A);   // A K-major: idx16 = (k>>3)*33+row
    short* Gt     = (short*)(smem + LDS_GT);  // new_G row-major [32][264]
    float* r_mean = (float*)(smem + LDS_SC);
    float* r_rstd = r_mean + 32;
    float* r_comb = r_rstd + 32;
    float* bias_f = r_comb + 32;

    const int tid  = threadIdx.x;
    const int row0 = blockIdx.x * M_TILE;

    float* outH = out;
    float* outG = out + (size_t)BATCH * UNITS;
    float* outP = out + (size_t)2 * BATCH * UNITS;

    bias_f[tid] = bias[tid];

    // ---- phase 1: stage A (bf16, K-major), new_G + stats, oscillator
    // 8 lanes per row (tid>>3 = row, tid&7 = 32-col slice), coalesced loads.
    {
        const int lr = tid >> 3;
        const int p  = tid & 7;
        const int gr = row0 + lr;
        float s1 = 0.f, s2 = 0.f, sh = 0.f;
        #pragma unroll
        for (int i = 0; i < 8; ++i) {
            int c0 = i * 32 + p * 4;
            int pc = (c0 + 128) & 255;        // raw[:,c] = prev_h[:,(c+128)&255]
            float4 xi = *(const float4*)(inputs + (size_t)gr * UNITS + c0);
            float4 hp = *(const float4*)(prev_h + (size_t)gr * UNITS + pc);
            float4 gp = *(const float4*)(prev_G + (size_t)gr * UNITS + c0);
            // inputs bf16 at k=c0
            ushort4 xq; xq.x = f2b(xi.x); xq.y = f2b(xi.y); xq.z = f2b(xi.z); xq.w = f2b(xi.w);
            *(ushort4*)(Ak + ((c0 >> 3) * A_PAD + lr) * 8 + (c0 & 7)) = xq;
            // prev_h bf16 (orig order) at k=256+pc
            ushort4 hq; hq.x = f2b(hp.x); hq.y = f2b(hp.y); hq.z = f2b(hp.z); hq.w = f2b(hp.w);
            int kh = 256 + pc;
            *(ushort4*)(Ak + ((kh >> 3) * A_PAD + lr) * 8 + (pc & 7)) = hq;
            // new_G
            float4 ng;
            ng.x = 0.9f * gp.x + 0.1f * hp.x;
            ng.y = 0.9f * gp.y + 0.1f * hp.y;
            ng.z = 0.9f * gp.z + 0.1f * hp.z;
            ng.w = 0.9f * gp.w + 0.1f * hp.w;
            s1 += ng.x + ng.y + ng.z + ng.w;
            s2 += ng.x*ng.x + ng.y*ng.y + ng.z*ng.z + ng.w*ng.w;
            sh += hp.x + hp.y + hp.z + hp.w;
            *(float4*)(outG + (size_t)gr * UNITS + c0) = ng;      // output 1 (fp32)
            ushort4 gq; gq.x = f2b(ng.x); gq.y = f2b(ng.y); gq.z = f2b(ng.z); gq.w = f2b(ng.w);
            *(ushort4*)(Gt + lr * GT_STRIDE + c0) = gq;           // epilogue copy
        }
        #pragma unroll
        for (int off = 4; off > 0; off >>= 1) {
            s1 += __shfl_xor(s1, off, 64);
            s2 += __shfl_xor(s2, off, 64);
            sh += __shfl_xor(sh, off, 64);
        }
        if (p == 0) {
            float mean = s1 * (1.f / 256.f);
            float var  = s2 * (1.f / 256.f) - mean * mean;         // population var
            float rstd = 1.f / (sqrtf(fmaxf(var, 0.f)) + 1e-6f);
            float np   = prev_phase[gr] + 0.2513274122871834591f;  // 2*pi/25
            outP[gr] = np;                                          // output 2 (fp32)
            float comb = sinf(np) + 0.05f * (sh * (1.f / 256.f) - 0.1f);
            r_mean[lr] = mean; r_rstd[lr] = rstd; r_comb[lr] = comb;
        }
    }

    __syncthreads();   // Ak + Gt + scalars visible

    // ---- phase 2: GEMM z = [inputs|prev_h] @ [w_in;w_rec]  (bf16 MFMA)
    // 16x16x32: A[m=lane&15][k=q*8+j]; B[k=q*8+j][n=lane&15]; C: col=lane&15,row=q*4+reg
    const int l   = tid & 63;
    const int w   = tid >> 6;
    const int n16 = l & 15;
    const int q   = l >> 4;

    v4f acc[2][4];
    const v4f z4 = {0.f, 0.f, 0.f, 0.f};
    #pragma unroll
    for (int mi = 0; mi < 2; ++mi)
        #pragma unroll
        for (int t = 0; t < 4; ++t) acc[mi][t] = z4;

    // A read: idx16 = (s*4+q)*33 + mi*16 + n16  (contiguous 256B per q-group)
    const short* ap = Ak + (q * A_PAD + n16) * 8;
    // B read: ((s*16 + w*4+t)*64 + l)*8 shorts, lane-contiguous 1KB per load
    const short* bw = (const short*)Wp + ((size_t)(w * 4) * 64 + l) * 8;

    #pragma unroll 2
    for (int s = 0; s < 16; ++s) {
        v8s a0 = *(const v8s*)(ap + s * (4 * A_PAD * 8));
        v8s a1 = *(const v8s*)(ap + s * (4 * A_PAD * 8) + 128);
        #pragma unroll
        for (int t = 0; t < 4; ++t) {
            v8s b = *(const v8s*)(bw + (s * 16 + t) * 512);
            acc[0][t] = __builtin_amdgcn_mfma_f32_16x16x32_bf16(a0, b, acc[0][t], 0, 0, 0);
            acc[1][t] = __builtin_amdgcn_mfma_f32_16x16x32_bf16(a1, b, acc[1][t], 0, 0, 0);
        }
    }

    // ---- epilogue: field_effect * (dot+bias) -> elu -> inertia -> clip
    #pragma unroll
    for (int mi = 0; mi < 2; ++mi) {
        #pragma unroll
        for (int t = 0; t < 4; ++t) {
            int c = (w * 4 + t) * 16 + n16;
            float bz = bias_f[c];
            #pragma unroll
            for (int r = 0; r < 4; ++r) {
                int lr = mi * 16 + q * 4 + r;
                int gr = row0 + lr;
                float gval = b2f((ushort_t)Gt[lr * GT_STRIDE + c]);
                float gn = (gval - r_mean[lr]) * r_rstd[lr];
                float e2 = __expf(2.f * gn);                       // tanh via exp
                float th = 1.f - 2.f / (e2 + 1.f);
                float field = 1.f + 0.5f * r_comb[lr] * th;
                float z = (acc[mi][t][r] + bz) * field;
                float el = (z > 0.f) ? z : (__expf(z) - 1.f);
                int kh = 256 + c;
                float hprev = b2f((ushort_t)Ak[((kh >> 3) * A_PAD + lr) * 8 + (c & 7)]);
                float h = 0.9f * hprev + 0.1f * el;
                h = fminf(fmaxf(h, -20.f), 20.f);
                outH[(size_t)gr * UNITS + c] = h;                  // output 0 (fp32)
            }
        }
    }
}

extern "C" void kernel_launch(void* const* d_in, const int* in_sizes, int n_in,
                              void* d_out, int out_size, void* d_ws, size_t ws_size,
                              hipStream_t stream) {
    const float* inputs     = (const float*)d_in[0];
    const float* prev_h     = (const float*)d_in[1];
    const float* prev_G     = (const float*)d_in[2];
    const float* prev_phase = (const float*)d_in[3];
    const float* w_in       = (const float*)d_in[4];
    const float* w_rec      = (const float*)d_in[5];
    const float* bias       = (const float*)d_in[6];
    float* out    = (float*)d_out;
    ushort_t* Wp  = (ushort_t*)d_ws;       // 262,144 B packed bf16 weights

    pack_w<<<512, 256, 0, stream>>>(w_in, w_rec, Wp);
    fused_cell<<<BATCH / M_TILE, 256, 0, stream>>>(inputs, prev_h, prev_G,
                                                   prev_phase, Wp, bias, out);
}

// Round 5
// 317.229 us; speedup vs baseline: 1.0851x; 1.0026x over previous
//
#include <hip/hip_runtime.h>

typedef unsigned short ushort_t;
typedef short v8s __attribute__((ext_vector_type(8)));   // 8 bf16 (4 VGPRs)
typedef float v4f __attribute__((ext_vector_type(4)));   // MFMA acc / NT store

#define BATCH    65536
#define UNITS    256
#define M_TILE   32
#define A_PAD    33          // rows+1 pad per 16B-fragment column: breaks pow2 banks
#define GT_STRIDE 264
#define LDS_AK   0
#define LDS_AK_SZ (32 * A_PAD * 16)       // 16,896 B : prev_h bf16 [k>>3][row pad33][8]
#define LDS_GT   LDS_AK_SZ                // 32 x 264 bf16 new_G
#define LDS_GT_SZ (32 * GT_STRIDE * 2)    // 16,896 B
#define LDS_SC   (LDS_GT + LDS_GT_SZ)     // 33,792
#define LDS_TOT  (LDS_SC + 1408)          // 35,200 B -> 4 blocks/CU (16 waves)

__device__ __forceinline__ float b2f(ushort_t u) {
    union { unsigned int i; float f; } v; v.i = ((unsigned int)u) << 16; return v.f;
}
__device__ __forceinline__ ushort_t f2b(float f) {
    union { float f; unsigned int i; } v; v.f = f;
    unsigned int r = (v.i + 0x7fffu + ((v.i >> 16) & 1u)) >> 16;   // RNE
    return (ushort_t)r;
}

// ---- weight pre-pack: fp32 W[512][256] -> bf16 MFMA-fragment order ---------
// B frag for (kchunk s = k>>5, tile t = n>>4): lane l = q*16+n16 holds
// B[k = s*32+q*8+j][n = t*16+n16], j=0..7.  Layout [s][t][l][8] -> a wave's
// B load is base + l*16B: perfectly coalesced 1KB, sequential lines.
__global__ void pack_w(const float* __restrict__ w_in,
                       const float* __restrict__ w_rec,
                       ushort_t* __restrict__ Wp) {
    int gid = blockIdx.x * 256 + threadIdx.x;      // 0..131071
    int k = gid >> 8, n = gid & 255;
    float v = (k < 256) ? w_in[k * 256 + n] : w_rec[(k - 256) * 256 + n];
    int s = k >> 5, t = n >> 4;
    int lane = ((k >> 3) & 3) * 16 + (n & 15);
    Wp[(size_t)(((s * 16 + t) * 64) + lane) * 8 + (k & 7)] = f2b(v);
}

// ---- fused cell ------------------------------------------------------------
// HBM-duty-cycle fix: inputs (1/3 of read traffic) loaded INSIDE the K-loop
// (fp32 + inline f2b, L1-backed) so HBM reads span the compute phase instead
// of bursting in phase 1.  Phase 1 handles prev_h/prev_G only.  4 blocks/CU.
__global__ __launch_bounds__(256, 4)
void fused_cell(const float* __restrict__ inputs,
                const float* __restrict__ prev_h,
                const float* __restrict__ prev_G,
                const float* __restrict__ prev_phase,
                const ushort_t* __restrict__ Wp,
                const float* __restrict__ bias,
                float* __restrict__ out) {
    __shared__ __align__(16) char smem[LDS_TOT];
    short* Ak     = (short*)(smem + LDS_AK);  // prev_h bf16 K-major (orig order)
    short* Gt     = (short*)(smem + LDS_GT);  // new_G row-major [32][264]
    float* r_mean = (float*)(smem + LDS_SC);
    float* r_rstd = r_mean + 32;
    float* r_comb = r_rstd + 32;
    float* bias_f = r_comb + 32;

    const int tid  = threadIdx.x;
    const int row0 = blockIdx.x * M_TILE;

    float* outH = out;
    float* outG = out + (size_t)BATCH * UNITS;
    float* outP = out + (size_t)2 * BATCH * UNITS;

    bias_f[tid] = bias[tid];

    const int l   = tid & 63;
    const int w   = tid >> 6;
    const int n16 = l & 15;
    const int q   = l >> 4;

    const float* ainp0 = inputs + (size_t)(row0 + n16) * UNITS + q * 8;       // mi=0
    const float* ainp1 = ainp0 + 16 * UNITS;                                   // mi=1
    const short* bw    = (const short*)Wp + ((size_t)(w * 4) * 64 + l) * 8;

    // s=0 operand prefetch: issued before phase 1 so latency hides under it
    float4 pA00 = *(const float4*)(ainp0);
    float4 pA01 = *(const float4*)(ainp0 + 4);
    float4 pA10 = *(const float4*)(ainp1);
    float4 pA11 = *(const float4*)(ainp1 + 4);
    v8s pB[4];
    #pragma unroll
    for (int tt = 0; tt < 4; ++tt) pB[tt] = *(const v8s*)(bw + tt * 512);

    // ---- phase 1: new_G = 0.9*prev_G + 0.1*roll(prev_h), stats, oscillator
    // 8 lanes per row (tid>>3 = row, tid&7 = 32-col slice), coalesced loads.
    {
        const int lr = tid >> 3;
        const int p  = tid & 7;
        const int gr = row0 + lr;
        float s1 = 0.f, s2 = 0.f, sh = 0.f;
        #pragma unroll
        for (int i = 0; i < 8; ++i) {
            int c0 = i * 32 + p * 4;
            int pc = (c0 + 128) & 255;        // raw[:,c] = prev_h[:,(c+128)&255]
            float4 hp = *(const float4*)(prev_h + (size_t)gr * UNITS + pc);
            float4 gp = *(const float4*)(prev_G + (size_t)gr * UNITS + c0);
            float4 ng;
            ng.x = 0.9f * gp.x + 0.1f * hp.x;
            ng.y = 0.9f * gp.y + 0.1f * hp.y;
            ng.z = 0.9f * gp.z + 0.1f * hp.z;
            ng.w = 0.9f * gp.w + 0.1f * hp.w;
            s1 += ng.x + ng.y + ng.z + ng.w;
            s2 += ng.x*ng.x + ng.y*ng.y + ng.z*ng.z + ng.w*ng.w;
            sh += hp.x + hp.y + hp.z + hp.w;
            v4f ngv; ngv[0] = ng.x; ngv[1] = ng.y; ngv[2] = ng.z; ngv[3] = ng.w;
            __builtin_nontemporal_store(ngv, (v4f*)(outG + (size_t)gr * UNITS + c0));
            ushort4 gq; gq.x = f2b(ng.x); gq.y = f2b(ng.y); gq.z = f2b(ng.z); gq.w = f2b(ng.w);
            *(ushort4*)(Gt + lr * GT_STRIDE + c0) = gq;           // epilogue copy
            ushort4 hq; hq.x = f2b(hp.x); hq.y = f2b(hp.y); hq.z = f2b(hp.z); hq.w = f2b(hp.w);
            *(ushort4*)(Ak + ((pc >> 3) * A_PAD + lr) * 8 + (pc & 7)) = hq;
        }
        #pragma unroll
        for (int off = 4; off > 0; off >>= 1) {
            s1 += __shfl_xor(s1, off, 64);
            s2 += __shfl_xor(s2, off, 64);
            sh += __shfl_xor(sh, off, 64);
        }
        if (p == 0) {
            float mean = s1 * (1.f / 256.f);
            float var  = s2 * (1.f / 256.f) - mean * mean;         // population var
            float rstd = 1.f / (sqrtf(fmaxf(var, 0.f)) + 1e-6f);
            float np   = prev_phase[gr] + 0.2513274122871834591f;  // 2*pi/25
            __builtin_nontemporal_store(np, outP + gr);            // output 2 (fp32)
            float comb = sinf(np) + 0.05f * (sh * (1.f / 256.f) - 0.1f);
            r_mean[lr] = mean; r_rstd[lr] = rstd; r_comb[lr] = comb;
        }
    }

    __syncthreads();   // Ak + Gt + scalars visible

    // ---- phase 2: GEMM z = [inputs|prev_h] @ [w_in;w_rec]  (bf16 MFMA)
    // 16x16x32: A[m=lane&15][k=q*8+j]; B[k=q*8+j][n=lane&15]; C: col=lane&15,row=q*4+reg
    // Each wave: all 32 rows x 64 cols (acc[2][4]); B fragment read by ONE wave.
    v4f acc[2][4];
    const v4f z4 = {0.f, 0.f, 0.f, 0.f};
    #pragma unroll
    for (int mi = 0; mi < 2; ++mi)
        #pragma unroll
        for (int tt = 0; tt < 4; ++tt) acc[mi][tt] = z4;

    #pragma unroll
    for (int s = 0; s < 16; ++s) {
        v8s a0, a1;
        if (s < 8) {
            float4 f00, f01, f10, f11;
            if (s == 0) { f00 = pA00; f01 = pA01; f10 = pA10; f11 = pA11; }
            else {
                f00 = *(const float4*)(ainp0 + s * 32);
                f01 = *(const float4*)(ainp0 + s * 32 + 4);
                f10 = *(const float4*)(ainp1 + s * 32);
                f11 = *(const float4*)(ainp1 + s * 32 + 4);
            }
            a0[0] = (short)f2b(f00.x); a0[1] = (short)f2b(f00.y);
            a0[2] = (short)f2b(f00.z); a0[3] = (short)f2b(f00.w);
            a0[4] = (short)f2b(f01.x); a0[5] = (short)f2b(f01.y);
            a0[6] = (short)f2b(f01.z); a0[7] = (short)f2b(f01.w);
            a1[0] = (short)f2b(f10.x); a1[1] = (short)f2b(f10.y);
            a1[2] = (short)f2b(f10.z); a1[3] = (short)f2b(f10.w);
            a1[4] = (short)f2b(f11.x); a1[5] = (short)f2b(f11.y);
            a1[6] = (short)f2b(f11.z); a1[7] = (short)f2b(f11.w);
        } else {
            const short* ap = Ak + ((s - 8) * 4 + q) * (A_PAD * 8);
            a0 = *(const v8s*)(ap + n16 * 8);
            a1 = *(const v8s*)(ap + (16 + n16) * 8);
        }
        #pragma unroll
        for (int tt = 0; tt < 4; ++tt) {
            v8s b = (s == 0) ? pB[tt] : *(const v8s*)(bw + (s * 16 + tt) * 512);
            acc[0][tt] = __builtin_amdgcn_mfma_f32_16x16x32_bf16(a0, b, acc[0][tt], 0, 0, 0);
            acc[1][tt] = __builtin_amdgcn_mfma_f32_16x16x32_bf16(a1, b, acc[1][tt], 0, 0, 0);
        }
    }

    // ---- epilogue: field_effect * (dot+bias) -> elu -> inertia -> clip
    #pragma unroll
    for (int mi = 0; mi < 2; ++mi) {
        #pragma unroll
        for (int tt = 0; tt < 4; ++tt) {
            int c = (w * 4 + tt) * 16 + n16;
            float bz = bias_f[c];
            #pragma unroll
            for (int r = 0; r < 4; ++r) {
                int lr = mi * 16 + q * 4 + r;
                int gr = row0 + lr;
                float gval = b2f((ushort_t)Gt[lr * GT_STRIDE + c]);
                float gn = (gval - r_mean[lr]) * r_rstd[lr];
                float e2 = __expf(2.f * gn);                       // tanh via exp
                float th = 1.f - 2.f / (e2 + 1.f);
                float field = 1.f + 0.5f * r_comb[lr] * th;
                float z = (acc[mi][tt][r] + bz) * field;
                float el = (z > 0.f) ? z : (__expf(z) - 1.f);
                float hprev = b2f((ushort_t)Ak[((c >> 3) * A_PAD + lr) * 8 + (c & 7)]);
                float h = 0.9f * hprev + 0.1f * el;
                h = fminf(fmaxf(h, -20.f), 20.f);
                __builtin_nontemporal_store(h, outH + (size_t)gr * UNITS + c);
            }
        }
    }
}

extern "C" void kernel_launch(void* const* d_in, const int* in_sizes, int n_in,
                              void* d_out, int out_size, void* d_ws, size_t ws_size,
                              hipStream_t stream) {
    const float* inputs     = (const float*)d_in[0];
    const float* prev_h     = (const float*)d_in[1];
    const float* prev_G     = (const float*)d_in[2];
    const float* prev_phase = (const float*)d_in[3];
    const float* w_in       = (const float*)d_in[4];
    const float* w_rec      = (const float*)d_in[5];
    const float* bias       = (const float*)d_in[6];
    float* out    = (float*)d_out;
    ushort_t* Wp  = (ushort_t*)d_ws;       // 262,144 B packed bf16 weights

    pack_w<<<512, 256, 0, stream>>>(w_in, w_rec, Wp);
    fused_cell<<<BATCH / M_TILE, 256, 0, stream>>>(inputs, prev_h, prev_G,
                                                   prev_phase, Wp, bias, out);
}